// Round 1
// baseline (375.611 us; speedup 1.0000x reference)
//
#include <hip/hip_runtime.h>
#include <cmath>

#define EPSV 1e-5f

typedef short bf16x8 __attribute__((ext_vector_type(8)));
typedef float f32x4 __attribute__((ext_vector_type(4)));

__device__ __forceinline__ unsigned short f2bf(float f) {
  unsigned u = __float_as_uint(f);
  unsigned r = ((u >> 16) & 1u) + 0x7FFFu;   // RTNE
  return (unsigned short)((u + r) >> 16);
}

__device__ __forceinline__ void async16(const void* g, void* l) {
  __builtin_amdgcn_global_load_lds(
      (const __attribute__((address_space(1))) unsigned int*)g,
      (__attribute__((address_space(3))) unsigned int*)l, 16, 0, 0);
}

// ---------------- prep: weights fp32 -> bf16 (w0 re-laid phase-major, K 588->672) ---
__global__ void prep_conv(const float* __restrict__ w0, const float* __restrict__ w1,
                          const float* __restrict__ w2, unsigned short* __restrict__ w0b,
                          unsigned short* __restrict__ w1b, unsigned short* __restrict__ w2b) {
  int idx = blockIdx.x * 256 + threadIdx.x;
  if (idx < 512 * 672) {
    int o = idx / 672, c = idx - o * 672;
    int ph = c / 224, q = c - ph * 224;   // k = ph*224 + pair ; orig c = pair*3 + ph
    float v = (q < 196) ? w0[o * 588 + q * 3 + ph] : 0.f;
    w0b[o * 672 + c] = f2bf(v);
    return;
  }
  idx -= 512 * 672;
  if (idx < 384 * 512) { w1b[idx] = f2bf(w1[idx]); return; }
  idx -= 384 * 512;
  if (idx < 256 * 384) { w2b[idx] = f2bf(w2[idx]); }
}

// ---------------- prep: softmax(weight_mask) -> wm[16][144] ------------------------
__global__ void prep_wm(const float* __restrict__ wmask, float* __restrict__ wm) {
  int g = threadIdx.x >> 6, lane = threadIdx.x & 63;
  const float* row = wmask + g * 144;
  float v0 = row[lane], v1 = row[lane + 64];
  float v2 = (lane < 16) ? row[lane + 128] : -1e30f;
  float m = fmaxf(fmaxf(v0, v1), v2);
  for (int off = 32; off; off >>= 1) m = fmaxf(m, __shfl_xor(m, off));
  float e0 = expf(v0 - m), e1 = expf(v1 - m), e2 = (lane < 16) ? expf(v2 - m) : 0.f;
  float s = e0 + e1 + e2;
  for (int off = 32; off; off >>= 1) s += __shfl_xor(s, off);
  float inv = 1.f / s;
  wm[g * 144 + lane] = e0 * inv;
  wm[g * 144 + lane + 64] = e1 * inv;
  if (lane < 16) wm[g * 144 + lane + 128] = e2 * inv;
}

// ---------------- fused main ------------------------------------------------------
// LDS map (bytes), peak = exactly 160 KiB in layer-1 phase:
//  L0 : B0 dbuf [0,65536)  xc [65536,72704)  feat dbuf [72704,82944)  h0 [98304,163840)
//  L1 : B1 dbuf [0,49152)  h1 [49152,98304)  h0 live
//  L2 : B2 dbuf [0,32768)  h1 live
#define LDS_XC 65536u
#define LDS_FT 72704u
#define LDS_H0 98304u
#define LDS_H1 49152u

__launch_bounds__(512, 2)
__global__ void fused_main(const float* __restrict__ x, const float* __restrict__ b0,
                           const float* __restrict__ b1, const float* __restrict__ b2,
                           const unsigned short* __restrict__ w0b,
                           const unsigned short* __restrict__ w1b,
                           const unsigned short* __restrict__ w2b,
                           const float* __restrict__ wm, float* __restrict__ out) {
  __shared__ __align__(16) char lds[163840];
  const int tid = threadIdx.x;
  const int wv = tid >> 6, lane = tid & 63;
  const int quad = lane >> 4, l15 = lane & 15;
  const int r0 = blockIdx.x * 64;

  // ---- per-row xi/xj cache (14 each, fp32), with x[:,167]=0 override ----
  {
    int row = tid >> 3, idx = tid & 7;
    int r = r0 + row;
    int b = r / 144, p = r - b * 144;
    int h = p / 12, w = p - h * 12;
    const float* xb = x + b * 168;
    float* xi = (float*)(lds + LDS_XC) + row * 14;
    float* xj = (float*)(lds + LDS_XC + 3584) + row * 14;
    for (int ii = idx; ii < 14; ii += 8) {
      int i = ii * 12 + h;
      xi[ii] = (i == 167) ? 0.f : xb[i];
      int j = ii * 12 + w;
      xj[ii] = (j == 167) ? 0.f : xb[j];
    }
  }
  __syncthreads();

  // stage one 32-k B tile (rows n, 64B each, chunk rotate-swizzle) via global_load_lds
  auto stageB = [&](const unsigned short* wsrc, int rowstride, unsigned ldsbase, int kt, int ipw) {
    for (int i = 0; i < ipw; i++) {
      int blkid = wv * ipw + i;
      int nn = blkid * 16 + (lane >> 2);
      int cc = lane & 3;
      int q = (cc - nn) & 3;                       // inverse of write swizzle
      const char* g = (const char*)wsrc + nn * rowstride + kt * 64 + q * 16;
      async16(g, lds + ldsbase + blkid * 1024u + lane * 16u);
    }
  };

  // generate feat tile for K-step knxt (phase-major K layout: k = phase*224 + pair)
  auto stageF = [&](int knxt, unsigned fbase) {
    int row = tid >> 3, u = tid & 7;
    int ph = knxt / 7;
    int q0 = (knxt - ph * 7) * 32 + u * 4;
    int i1 = q0 / 14;
    int j1 = q0 - i1 * 14;
    const float* xi = (const float*)(lds + LDS_XC) + row * 14;
    const float* xj = (const float*)(lds + LDS_XC + 3584) + row * 14;
    unsigned short vs[4];
#pragma unroll
    for (int e = 0; e < 4; e++) {
      int q = q0 + e;
      float f = 0.f;
      if (q < 196) {
        float a = xi[i1], c = xj[j1];
        if (ph == 0) f = c - a;
        else {
          float rcp = __builtin_amdgcn_rcpf(a + c + EPSV);
          f = (ph == 1) ? (c - a) * rcp : c * rcp;
        }
      }
      vs[e] = f2bf(f);
      if (++j1 == 14) { j1 = 0; i1++; }
    }
    *(unsigned long long*)(lds + fbase + row * 80u + u * 8u) =
        (unsigned long long)vs[0] | ((unsigned long long)vs[1] << 16) |
        ((unsigned long long)vs[2] << 32) | ((unsigned long long)vs[3] << 48);
  };

  // =================== Layer 0 : feat(672) -> 512 ===================
  {
    f32x4 acc[4][4];
#pragma unroll
    for (int a = 0; a < 4; a++)
#pragma unroll
      for (int c = 0; c < 4; c++) acc[a][c] = f32x4{0.f, 0.f, 0.f, 0.f};

    stageB(w0b, 1344, 0u, 0, 4);
    stageF(0, LDS_FT);
    __syncthreads();
    for (int kt = 0; kt < 21; kt++) {
      int nxt = kt + 1;
      if (nxt < 21) {
        stageB(w0b, 1344, (nxt & 1) * 32768u, nxt, 4);
        stageF(nxt, LDS_FT + (nxt & 1) * 5120u);
      }
      unsigned fb = LDS_FT + (kt & 1) * 5120u;
      unsigned bb = (kt & 1) * 32768u;
      bf16x8 af[4], bfr[4];
#pragma unroll
      for (int rt = 0; rt < 4; rt++)
        af[rt] = *(const bf16x8*)(lds + fb + (rt * 16 + l15) * 80u + quad * 16u);
#pragma unroll
      for (int ct = 0; ct < 4; ct++) {
        int n = wv * 64 + ct * 16 + l15;
        bfr[ct] = *(const bf16x8*)(lds + bb + n * 64u + ((quad + n) & 3) * 16u);
      }
#pragma unroll
      for (int rt = 0; rt < 4; rt++)
#pragma unroll
        for (int ct = 0; ct < 4; ct++)
          acc[rt][ct] = __builtin_amdgcn_mfma_f32_16x16x32_bf16(af[rt], bfr[ct], acc[rt][ct], 0, 0, 0);
      __syncthreads();
    }
    // prefetch layer-1 B tile 0 while writing h0
    stageB(w1b, 1024, 0u, 0, 3);
    // epilogue: bias+relu -> bf16 h0 (chunk-rotate swizzle, 64 chunks/row)
#pragma unroll
    for (int ct = 0; ct < 4; ct++) {
      int col = wv * 64 + ct * 16 + l15;
      float bias = b0[col];
      int kb = col >> 3, cr = (col & 7) * 2;
#pragma unroll
      for (int rt = 0; rt < 4; rt++)
#pragma unroll
        for (int vi = 0; vi < 4; vi++) {
          int rowm = rt * 16 + quad * 4 + vi;
          float v = fmaxf(acc[rt][ct][vi] + bias, 0.f);
          *(unsigned short*)(lds + LDS_H0 + rowm * 1024u + ((kb + rowm) & 63) * 16u + cr) = f2bf(v);
        }
    }
  }
  __syncthreads();

  // =================== Layer 1 : 512 -> 384 ===================
  {
    f32x4 acc[4][3];
#pragma unroll
    for (int a = 0; a < 4; a++)
#pragma unroll
      for (int c = 0; c < 3; c++) acc[a][c] = f32x4{0.f, 0.f, 0.f, 0.f};

    for (int kt = 0; kt < 16; kt++) {
      int nxt = kt + 1;
      if (nxt < 16) stageB(w1b, 1024, (nxt & 1) * 24576u, nxt, 3);
      unsigned bb = (kt & 1) * 24576u;
      bf16x8 af[4], bfr[3];
#pragma unroll
      for (int rt = 0; rt < 4; rt++) {
        int m = rt * 16 + l15;
        af[rt] = *(const bf16x8*)(lds + LDS_H0 + m * 1024u + (((kt * 4 + quad) + m) & 63) * 16u);
      }
#pragma unroll
      for (int ct = 0; ct < 3; ct++) {
        int n = wv * 48 + ct * 16 + l15;
        bfr[ct] = *(const bf16x8*)(lds + bb + n * 64u + ((quad + n) & 3) * 16u);
      }
#pragma unroll
      for (int rt = 0; rt < 4; rt++)
#pragma unroll
        for (int ct = 0; ct < 3; ct++)
          acc[rt][ct] = __builtin_amdgcn_mfma_f32_16x16x32_bf16(af[rt], bfr[ct], acc[rt][ct], 0, 0, 0);
      __syncthreads();
    }
    stageB(w2b, 768, 0u, 0, 2);  // prefetch layer-2 B tile 0
    // epilogue -> h1 (48 chunks/row, rotate mod 48)
#pragma unroll
    for (int ct = 0; ct < 3; ct++) {
      int col = wv * 48 + ct * 16 + l15;
      float bias = b1[col];
      int kb = col >> 3, cr = (col & 7) * 2;
#pragma unroll
      for (int rt = 0; rt < 4; rt++)
#pragma unroll
        for (int vi = 0; vi < 4; vi++) {
          int rowm = rt * 16 + quad * 4 + vi;
          int s = kb + rowm;
          if (s >= 48) s -= 48;
          if (s >= 48) s -= 48;
          float v = fmaxf(acc[rt][ct][vi] + bias, 0.f);
          *(unsigned short*)(lds + LDS_H1 + rowm * 768u + s * 16u + cr) = f2bf(v);
        }
    }
  }
  __syncthreads();

  // =================== Layer 2 : 384 -> 256, fused weighted reduction ==============
  {
    f32x4 acc[4][2];
#pragma unroll
    for (int a = 0; a < 4; a++)
#pragma unroll
      for (int c = 0; c < 2; c++) acc[a][c] = f32x4{0.f, 0.f, 0.f, 0.f};

    for (int kt = 0; kt < 12; kt++) {
      int nxt = kt + 1;
      if (nxt < 12) stageB(w2b, 768, (nxt & 1) * 16384u, nxt, 2);
      unsigned bb = (kt & 1) * 16384u;
      bf16x8 af[4], bfr[2];
#pragma unroll
      for (int rt = 0; rt < 4; rt++) {
        int m = rt * 16 + l15;
        int s = (kt * 4 + quad) + m;
        if (s >= 48) s -= 48;
        if (s >= 48) s -= 48;
        af[rt] = *(const bf16x8*)(lds + LDS_H1 + m * 768u + s * 16u);
      }
#pragma unroll
      for (int ct = 0; ct < 2; ct++) {
        int n = wv * 32 + ct * 16 + l15;
        bfr[ct] = *(const bf16x8*)(lds + bb + n * 64u + ((quad + n) & 3) * 16u);
      }
#pragma unroll
      for (int rt = 0; rt < 4; rt++)
#pragma unroll
        for (int ct = 0; ct < 2; ct++)
          acc[rt][ct] = __builtin_amdgcn_mfma_f32_16x16x32_bf16(af[rt], bfr[ct], acc[rt][ct], 0, 0, 0);
      __syncthreads();
    }

    // epilogue: relu(h2+b2) * softmax-wm, reduce over rows, atomicAdd into out
    int bi = r0 / 144;
    int boundary = (bi + 1) * 144;
#pragma unroll
    for (int ct = 0; ct < 2; ct++) {
      int col = wv * 32 + ct * 16 + l15;
      float bias = b2[col];
      const float* wmg = wm + (col >> 4) * 144;
      float s0 = 0.f, s1 = 0.f;
#pragma unroll
      for (int rt = 0; rt < 4; rt++)
#pragma unroll
        for (int vi = 0; vi < 4; vi++) {
          int r = r0 + rt * 16 + quad * 4 + vi;
          float v = fmaxf(acc[rt][ct][vi] + bias, 0.f);
          if (r < boundary) s0 += v * wmg[r - bi * 144];
          else              s1 += v * wmg[r - boundary];
        }
      s0 += __shfl_xor(s0, 16); s0 += __shfl_xor(s0, 32);
      s1 += __shfl_xor(s1, 16); s1 += __shfl_xor(s1, 32);
      if (quad == 0) {
        atomicAdd(out + bi * 256 + col, s0);
        if (boundary < r0 + 64) atomicAdd(out + (bi + 1) * 256 + col, s1);
      }
    }
  }
}

extern "C" void kernel_launch(void* const* d_in, const int* in_sizes, int n_in,
                              void* d_out, int out_size, void* d_ws, size_t ws_size,
                              hipStream_t stream) {
  (void)in_sizes; (void)n_in; (void)ws_size;
  const float* x     = (const float*)d_in[0];
  const float* w0    = (const float*)d_in[1];
  const float* b0    = (const float*)d_in[2];
  const float* w1    = (const float*)d_in[3];
  const float* b1    = (const float*)d_in[4];
  const float* w2    = (const float*)d_in[5];
  const float* b2    = (const float*)d_in[6];
  const float* wmask = (const float*)d_in[7];
  float* out = (float*)d_out;
  char* ws = (char*)d_ws;
  float* wm = (float*)ws;                                        // 16*144*4 = 9216
  unsigned short* w0b = (unsigned short*)(ws + 9216);            // 512*672*2 = 688128
  unsigned short* w1b = (unsigned short*)(ws + 9216 + 688128);   // 384*512*2 = 393216
  unsigned short* w2b = (unsigned short*)(ws + 9216 + 688128 + 393216);  // 256*384*2

  hipMemsetAsync(d_out, 0, (size_t)out_size * sizeof(float), stream);
  prep_conv<<<2496, 256, 0, stream>>>(w0, w1, w2, w0b, w1b, w2b);
  prep_wm<<<1, 1024, 0, stream>>>(wmask, wm);
  fused_main<<<2304, 512, 0, stream>>>(x, b0, b1, b2, w0b, w1b, w2b, wm, out);
}